// Round 4
// baseline (234.499 us; speedup 1.0000x reference)
//
#include <hip/hip_runtime.h>
#include <hip/hip_bf16.h>
#include <hip/hip_fp16.h>

// 3-layer GCN + FC head. No-prescan padded two-pass radix preprocessing:
//   k_init  : cursors = fixed region starts (super s: s*capS; bucket b: b*capB)
//   k_bin1  : bin edges by dst-super (25 regions), LDS rank, clustered writes
//   k_bin2  : bin by dst-bucket within super (782 padded regions; no div)
//   k_sortb2: per-bucket counting sort -> padded ssort + row2[n]={beg,end} + dinv
//             + fused p4 = dinv*x
// Layers:
//   k_l1g   : agg3 -> relu(.@W11+b11) -> @W12*dinv -> g (fp16)  [32 lanes/node]
//   k_agg8g : gather g (8 lanes/node, 8B/lane, 8-deep) -> h=relu(dinv*acc+b12)
//             -> (h@W13)*dinv -> gout (fp16)  [LDS gemv fusion]
//   k_agg8_fc: gather gout -> relu(dinv*acc+b13).fcw + fcb -> out

#define RBITS  7
#define RNODES 128
#define SBITS  12
#define SNODES 4096
#define BPS    32
#define SMAX   32
#define CE     4096
#define EPT    16

// ---------- preprocessing ----------
__global__ void k_init(int S, int B, int capS, int capB,
                       int* __restrict__ gcur1, int* __restrict__ gcur2) {
    int t = blockIdx.x * blockDim.x + threadIdx.x;
    if (t < S) gcur1[t] = t * capS;
    if (t < B) gcur2[t] = t * capB;
}

__global__ void k_bin1(const int* __restrict__ src, const int* __restrict__ dst, int E, int S,
                       int* __restrict__ gcur1, unsigned* __restrict__ binned1) {
    __shared__ int cnt[SMAX * 8];
    __shared__ int repOff[SMAX * 8];
    __shared__ int runS[SMAX];
    int tid = threadIdx.x, rep = tid & 7;
    for (int i = tid; i < SMAX * 8; i += 256) cnt[i] = 0;
    __syncthreads();
    int e0 = blockIdx.x * CE;
    int pk[EPT], rnk[EPT], sup[EPT];
#pragma unroll
    for (int j = 0; j < EPT; j++) {
        int e = e0 + j * 256 + tid;
        if (e < E) {
            int d = __builtin_nontemporal_load(dst + e);
            sup[j] = d >> SBITS;
            pk[j]  = (__builtin_nontemporal_load(src + e) << SBITS) | (d & (SNODES - 1));
            rnk[j] = atomicAdd(&cnt[sup[j] * 8 + rep], 1);
        } else sup[j] = -1;
    }
    __syncthreads();
    if (tid < S) {
        int tot = 0;
#pragma unroll
        for (int r = 0; r < 8; r++) { repOff[tid * 8 + r] = tot; tot += cnt[tid * 8 + r]; }
        runS[tid] = tot ? atomicAdd(&gcur1[tid], tot) : 0;
    }
    __syncthreads();
#pragma unroll
    for (int j = 0; j < EPT; j++)
        if (sup[j] >= 0)
            binned1[runS[sup[j]] + repOff[sup[j] * 8 + rep] + rnk[j]] = (unsigned)pk[j];
}

__global__ void k_bin2(const unsigned* __restrict__ binned1, const int* __restrict__ fillEnd,
                       int S, int capS, int* __restrict__ gcur2, unsigned* __restrict__ binned2) {
    __shared__ int send[SMAX];
    __shared__ int cnt[64 * 4];
    __shared__ int repOff[64 * 4];
    __shared__ int runS[64];
    int tid = threadIdx.x, rep = tid & 3;
    if (tid < S) send[tid] = fillEnd[tid];
    for (int i = tid; i < 64 * 4; i += 256) cnt[i] = 0;
    __syncthreads();
    int i0 = blockIdx.x * CE;
    int s0 = i0 / capS;
    int bnd = (s0 + 1) * capS;      // a block spans at most 2 super-regions
    int Sc = S * capS;
    unsigned pk[EPT];
    int rnk[EPT], rb[EPT];
#pragma unroll
    for (int j = 0; j < EPT; j++) {
        int idx = i0 + j * 256 + tid;
        rb[j] = -1;
        if (idx < Sc) {
            int sp = s0 + (idx >= bnd ? 1 : 0);
            if (idx < send[sp]) {
                unsigned p = __builtin_nontemporal_load(binned1 + idx);
                int relB = ((sp - s0) << 5) | ((p >> RBITS) & (BPS - 1));
                pk[j] = p; rb[j] = relB;
                rnk[j] = atomicAdd(&cnt[relB * 4 + rep], 1);
            }
        }
    }
    __syncthreads();
    if (tid < 64) {
        int tot = 0;
#pragma unroll
        for (int r = 0; r < 4; r++) { repOff[tid * 4 + r] = tot; tot += cnt[tid * 4 + r]; }
        int sp = s0 + (tid >> 5);
        if (tot && sp < S) {
            int gb = sp * BPS + (tid & (BPS - 1));
            runS[tid] = atomicAdd(&gcur2[gb], tot);
        }
    }
    __syncthreads();
#pragma unroll
    for (int j = 0; j < EPT; j++)
        if (rb[j] >= 0) {
            unsigned p = pk[j];
            binned2[runS[rb[j]] + repOff[rb[j] * 4 + rep] + rnk[j]] =
                ((p >> SBITS) << RBITS) | (p & (RNODES - 1));
        }
}

// per-bucket counting sort -> padded ssort, row2[n]={beg,end}, dinv, p4=dinv*x
__global__ void k_sortb2(const unsigned* __restrict__ binned2, const int* __restrict__ gcur2,
                         int capB, int N, int* __restrict__ ssort,
                         int2* __restrict__ row2, float* __restrict__ dinv,
                         const float* __restrict__ x, float4* __restrict__ p4) {
    __shared__ int cnt[RNODES];
    __shared__ int loc[RNODES];
    int b = blockIdx.x, tid = threadIdx.x;
    int beg = b * capB, end = gcur2[b];
    if (tid < RNODES) cnt[tid] = 0;
    __syncthreads();
    for (int idx = beg + tid; idx < end; idx += 256)
        atomicAdd(&cnt[__builtin_nontemporal_load(binned2 + idx) & (RNODES - 1)], 1);
    __syncthreads();
    if (tid < RNODES) loc[tid] = cnt[tid];
    __syncthreads();
    for (int off = 1; off < RNODES; off <<= 1) {
        int v = 0;
        if (tid < RNODES && tid >= off) v = loc[tid - off];
        __syncthreads();
        if (tid < RNODES) loc[tid] += v;
        __syncthreads();
    }
    int n0 = b << RBITS;
    if (tid < RNODES) {
        int excl = loc[tid] - cnt[tid];
        loc[tid] = beg + excl;
        int n = n0 + tid;
        if (n < N) {
            row2[n] = make_int2(beg + excl, beg + excl + cnt[tid]);
            float dv = rsqrtf((float)cnt[tid] + 1.0f);   // +1 self loop
            dinv[n] = dv;
            p4[n] = make_float4(x[n * 3] * dv, x[n * 3 + 1] * dv,
                                x[n * 3 + 2] * dv, 0.f);
        }
    }
    if (tid < RNODES) cnt[tid] = 0;               // reuse as cursor
    __syncthreads();
    for (int idx = beg + tid; idx < end; idx += 256) {
        unsigned p = __builtin_nontemporal_load(binned2 + idx);
        int dl = (int)(p & (RNODES - 1));
        int r  = atomicAdd(&cnt[dl], 1);
        ssort[loc[dl] + r] = (int)(p >> RBITS);
    }
}

// ---------- layer 1 (+W12 fused) ----------
__global__ void k_l1g(const int2* __restrict__ row2, const int* __restrict__ ssort,
                      const float4* __restrict__ p4, const float* __restrict__ dinv,
                      const float* __restrict__ W1, const float* __restrict__ b1,
                      const float* __restrict__ W2, __half* __restrict__ g2, int N) {
    __shared__ float sW1[96];
    __shared__ float sb1[32];
    __shared__ float sW2[1024];
    __shared__ float sh1[256];
    int tid = threadIdx.x;
    for (int i = tid; i < 1024; i += 256) sW2[i] = W2[i];
    if (tid < 96) sW1[tid] = W1[tid];
    if (tid < 32) sb1[tid] = b1[tid];
    __syncthreads();
    int t = blockIdx.x * 256 + tid;
    int n = t >> 5, c = t & 31;
    bool active = (n < N);
    float ax = 0.f, ay = 0.f, az = 0.f;
    float di = 0.f;
    if (active) {
        int2 r = row2[n];
        for (int idx = r.x + c; idx < r.y; idx += 32) {
            float4 q = p4[__builtin_nontemporal_load(ssort + idx)];
            ax += q.x; ay += q.y; az += q.z;
        }
    }
#pragma unroll
    for (int off = 16; off; off >>= 1) {
        ax += __shfl_xor(ax, off, 32);
        ay += __shfl_xor(ay, off, 32);
        az += __shfl_xor(az, off, 32);
    }
    float h1 = 0.f;
    if (active) {
        float4 me = p4[n];
        di = dinv[n];
        ax = di * (ax + me.x); ay = di * (ay + me.y); az = di * (az + me.z);
        h1 = fmaxf(ax * sW1[c] + ay * sW1[32 + c] + az * sW1[64 + c] + sb1[c], 0.f);
    }
    sh1[tid] = h1;
    __syncthreads();
    if (!active) return;
    const float* hr = sh1 + (tid >> 5) * 32;
    float acc = 0.f;
#pragma unroll
    for (int k = 0; k < 32; k++) acc += hr[k] * sW2[k * 32 + c];
    g2[(size_t)n * 32 + c] = __float2half_rn(acc * di);
}

// unpack 8B (4 fp16 channels) and accumulate into one bank
__device__ __forceinline__ void acc4(uint2 q, float& x, float& y, float& z, float& w) {
    __half2 h01, h23;
    __builtin_memcpy(&h01, &q.x, 4);
    __builtin_memcpy(&h23, &q.y, 4);
    float2 f01 = __half22float2(h01);
    float2 f23 = __half22float2(h23);
    x += f01.x; y += f01.y; z += f23.x; w += f23.y;
}

// ---------- layer 2 aggregate + W13 gemv fused ----------
// 8 lanes/node, lane = 4 channels (8B load), 8-deep bursts (8 rows/wave-instr),
// ssort next-chunk prefetch; h staged in LDS (pad 33), gemv -> gout fp16.
__global__ void k_agg8g(const int2* __restrict__ row2, const int* __restrict__ ssort,
                        const uint2* __restrict__ G, const float* __restrict__ dinv,
                        const float* __restrict__ bias, const float* __restrict__ W3,
                        uint2* __restrict__ GO, int N) {
    __shared__ float sW[1024];
    __shared__ float sh[32 * 33];
    int tid = threadIdx.x;
    for (int i = tid; i < 1024; i += 256) sW[i] = W3[i];
    int t = blockIdx.x * 256 + tid;
    int n = t >> 3, l = t & 7;
    int c0 = l * 4;
    bool act = (n < N);
    float di = 0.f;
    if (act) {
        int2 r = row2[n];
        int beg = r.x, end = r.y;
        float a0x=0,a0y=0,a0z=0,a0w=0, a1x=0,a1y=0,a1z=0,a1w=0;
        float a2x=0,a2y=0,a2z=0,a2w=0, a3x=0,a3y=0,a3z=0,a3w=0;
        float a4x=0,a4y=0,a4z=0,a4w=0, a5x=0,a5y=0,a5z=0,a5w=0;
        float a6x=0,a6y=0,a6z=0,a6w=0, a7x=0,a7y=0,a7z=0,a7w=0;
        int base = beg;
        int m = end - base; if (m > 8) m = 8;
        int myS = (m > 0 && l < m) ? __builtin_nontemporal_load(ssort + base + l) : 0;
        while (base < end) {
            int nbase = base + 8;
            int nm = end - nbase; if (nm > 8) nm = 8;
            int nS = (nm > 0 && l < nm) ? __builtin_nontemporal_load(ssort + nbase + l) : 0;
            int i = 0;
            if (m == 8) {
                int s0 = __shfl(myS, 0, 8);
                int s1 = __shfl(myS, 1, 8);
                int s2 = __shfl(myS, 2, 8);
                int s3 = __shfl(myS, 3, 8);
                int s4 = __shfl(myS, 4, 8);
                int s5 = __shfl(myS, 5, 8);
                int s6 = __shfl(myS, 6, 8);
                int s7 = __shfl(myS, 7, 8);
                uint2 q0 = G[(size_t)s0 * 8 + l];
                uint2 q1 = G[(size_t)s1 * 8 + l];
                uint2 q2 = G[(size_t)s2 * 8 + l];
                uint2 q3 = G[(size_t)s3 * 8 + l];
                uint2 q4 = G[(size_t)s4 * 8 + l];
                uint2 q5 = G[(size_t)s5 * 8 + l];
                uint2 q6 = G[(size_t)s6 * 8 + l];
                uint2 q7 = G[(size_t)s7 * 8 + l];
                acc4(q0, a0x, a0y, a0z, a0w);
                acc4(q1, a1x, a1y, a1z, a1w);
                acc4(q2, a2x, a2y, a2z, a2w);
                acc4(q3, a3x, a3y, a3z, a3w);
                acc4(q4, a4x, a4y, a4z, a4w);
                acc4(q5, a5x, a5y, a5z, a5w);
                acc4(q6, a6x, a6y, a6z, a6w);
                acc4(q7, a7x, a7y, a7z, a7w);
                i = 8;
            }
            for (; i + 4 <= m; i += 4) {
                int s0 = __shfl(myS, i,     8);
                int s1 = __shfl(myS, i + 1, 8);
                int s2 = __shfl(myS, i + 2, 8);
                int s3 = __shfl(myS, i + 3, 8);
                uint2 q0 = G[(size_t)s0 * 8 + l];
                uint2 q1 = G[(size_t)s1 * 8 + l];
                uint2 q2 = G[(size_t)s2 * 8 + l];
                uint2 q3 = G[(size_t)s3 * 8 + l];
                acc4(q0, a0x, a0y, a0z, a0w);
                acc4(q1, a1x, a1y, a1z, a1w);
                acc4(q2, a2x, a2y, a2z, a2w);
                acc4(q3, a3x, a3y, a3z, a3w);
            }
            for (; i < m; i++) {
                int s = __shfl(myS, i, 8);
                uint2 q = G[(size_t)s * 8 + l];
                acc4(q, a0x, a0y, a0z, a0w);
            }
            base = nbase; m = nm; myS = nS;
        }
        float sfx, sfy, sfz, sfw;
        {
            uint2 qs = G[(size_t)n * 8 + l];
            __half2 h01, h23;
            __builtin_memcpy(&h01, &qs.x, 4);
            __builtin_memcpy(&h23, &qs.y, 4);
            float2 f01 = __half22float2(h01);
            float2 f23 = __half22float2(h23);
            sfx = f01.x; sfy = f01.y; sfz = f23.x; sfw = f23.y;
        }
        float s0 = (((a0x + a1x) + (a2x + a3x)) + ((a4x + a5x) + (a6x + a7x))) + sfx;
        float s1 = (((a0y + a1y) + (a2y + a3y)) + ((a4y + a5y) + (a6y + a7y))) + sfy;
        float s2 = (((a0z + a1z) + (a2z + a3z)) + ((a4z + a5z) + (a6z + a7z))) + sfz;
        float s3 = (((a0w + a1w) + (a2w + a3w)) + ((a4w + a5w) + (a6w + a7w))) + sfw;
        di = dinv[n];
        int nn = tid >> 3;
        float* hrow = sh + nn * 33 + c0;
        hrow[0] = fmaxf(di * s0 + bias[c0],     0.f);
        hrow[1] = fmaxf(di * s1 + bias[c0 + 1], 0.f);
        hrow[2] = fmaxf(di * s2 + bias[c0 + 2], 0.f);
        hrow[3] = fmaxf(di * s3 + bias[c0 + 3], 0.f);
    }
    __syncthreads();
    if (!act) return;
    const float* hr = sh + (tid >> 3) * 33;
    float g0 = 0.f, g1 = 0.f, g2 = 0.f, g3 = 0.f;
#pragma unroll
    for (int k = 0; k < 32; k++) {
        float hv = hr[k];
        float4 w = *(const float4*)(sW + k * 32 + c0);
        g0 += hv * w.x; g1 += hv * w.y; g2 += hv * w.z; g3 += hv * w.w;
    }
    __half2 o01 = __floats2half2_rn(g0 * di, g1 * di);
    __half2 o23 = __floats2half2_rn(g2 * di, g3 * di);
    uint2 st;
    __builtin_memcpy(&st.x, &o01, 4);
    __builtin_memcpy(&st.y, &o23, 4);
    GO[(size_t)n * 8 + l] = st;
}

// ---------- layer 3 aggregate + FC head ----------
__global__ void k_agg8_fc(const int2* __restrict__ row2, const int* __restrict__ ssort,
                          const uint2* __restrict__ G, const float* __restrict__ dinv,
                          const float* __restrict__ bias, const float* __restrict__ fcw,
                          const float* __restrict__ fcb, float* __restrict__ out, int N) {
    int t = blockIdx.x * blockDim.x + threadIdx.x;
    int n = t >> 3, l = t & 7;
    if (n >= N) return;
    int2 r = row2[n];
    int beg = r.x, end = r.y;
    float a0x=0,a0y=0,a0z=0,a0w=0, a1x=0,a1y=0,a1z=0,a1w=0;
    float a2x=0,a2y=0,a2z=0,a2w=0, a3x=0,a3y=0,a3z=0,a3w=0;
    float a4x=0,a4y=0,a4z=0,a4w=0, a5x=0,a5y=0,a5z=0,a5w=0;
    float a6x=0,a6y=0,a6z=0,a6w=0, a7x=0,a7y=0,a7z=0,a7w=0;
    int base = beg;
    int m = end - base; if (m > 8) m = 8;
    int myS = (m > 0 && l < m) ? __builtin_nontemporal_load(ssort + base + l) : 0;
    while (base < end) {
        int nbase = base + 8;
        int nm = end - nbase; if (nm > 8) nm = 8;
        int nS = (nm > 0 && l < nm) ? __builtin_nontemporal_load(ssort + nbase + l) : 0;
        int i = 0;
        if (m == 8) {
            int s0 = __shfl(myS, 0, 8);
            int s1 = __shfl(myS, 1, 8);
            int s2 = __shfl(myS, 2, 8);
            int s3 = __shfl(myS, 3, 8);
            int s4 = __shfl(myS, 4, 8);
            int s5 = __shfl(myS, 5, 8);
            int s6 = __shfl(myS, 6, 8);
            int s7 = __shfl(myS, 7, 8);
            uint2 q0 = G[(size_t)s0 * 8 + l];
            uint2 q1 = G[(size_t)s1 * 8 + l];
            uint2 q2 = G[(size_t)s2 * 8 + l];
            uint2 q3 = G[(size_t)s3 * 8 + l];
            uint2 q4 = G[(size_t)s4 * 8 + l];
            uint2 q5 = G[(size_t)s5 * 8 + l];
            uint2 q6 = G[(size_t)s6 * 8 + l];
            uint2 q7 = G[(size_t)s7 * 8 + l];
            acc4(q0, a0x, a0y, a0z, a0w);
            acc4(q1, a1x, a1y, a1z, a1w);
            acc4(q2, a2x, a2y, a2z, a2w);
            acc4(q3, a3x, a3y, a3z, a3w);
            acc4(q4, a4x, a4y, a4z, a4w);
            acc4(q5, a5x, a5y, a5z, a5w);
            acc4(q6, a6x, a6y, a6z, a6w);
            acc4(q7, a7x, a7y, a7z, a7w);
            i = 8;
        }
        for (; i + 4 <= m; i += 4) {
            int s0 = __shfl(myS, i,     8);
            int s1 = __shfl(myS, i + 1, 8);
            int s2 = __shfl(myS, i + 2, 8);
            int s3 = __shfl(myS, i + 3, 8);
            uint2 q0 = G[(size_t)s0 * 8 + l];
            uint2 q1 = G[(size_t)s1 * 8 + l];
            uint2 q2 = G[(size_t)s2 * 8 + l];
            uint2 q3 = G[(size_t)s3 * 8 + l];
            acc4(q0, a0x, a0y, a0z, a0w);
            acc4(q1, a1x, a1y, a1z, a1w);
            acc4(q2, a2x, a2y, a2z, a2w);
            acc4(q3, a3x, a3y, a3z, a3w);
        }
        for (; i < m; i++) {
            int s = __shfl(myS, i, 8);
            uint2 q = G[(size_t)s * 8 + l];
            acc4(q, a0x, a0y, a0z, a0w);
        }
        base = nbase; m = nm; myS = nS;
    }
    float sfx, sfy, sfz, sfw;
    {
        uint2 qs = G[(size_t)n * 8 + l];
        __half2 h01, h23;
        __builtin_memcpy(&h01, &qs.x, 4);
        __builtin_memcpy(&h23, &qs.y, 4);
        float2 f01 = __half22float2(h01);
        float2 f23 = __half22float2(h23);
        sfx = f01.x; sfy = f01.y; sfz = f23.x; sfw = f23.y;
    }
    float s0 = (((a0x + a1x) + (a2x + a3x)) + ((a4x + a5x) + (a6x + a7x))) + sfx;
    float s1 = (((a0y + a1y) + (a2y + a3y)) + ((a4y + a5y) + (a6y + a7y))) + sfy;
    float s2 = (((a0z + a1z) + (a2z + a3z)) + ((a4z + a5z) + (a6z + a7z))) + sfz;
    float s3 = (((a0w + a1w) + (a2w + a3w)) + ((a4w + a5w) + (a6w + a7w))) + sfw;
    float di = dinv[n];
    int c0 = l * 4;
    float v = fmaxf(di * s0 + bias[c0],     0.f) * fcw[c0]
            + fmaxf(di * s1 + bias[c0 + 1], 0.f) * fcw[c0 + 1]
            + fmaxf(di * s2 + bias[c0 + 2], 0.f) * fcw[c0 + 2]
            + fmaxf(di * s3 + bias[c0 + 3], 0.f) * fcw[c0 + 3];
    v += __shfl_down(v, 4, 8);
    v += __shfl_down(v, 2, 8);
    v += __shfl_down(v, 1, 8);
    if (l == 0) out[n] = v + fcb[0];
}

extern "C" void kernel_launch(void* const* d_in, const int* in_sizes, int n_in,
                              void* d_out, int out_size, void* d_ws, size_t ws_size,
                              hipStream_t stream) {
    const float* x1  = (const float*)d_in[0];
    const int*   ei  = (const int*)d_in[1];
    const float* W11 = (const float*)d_in[2];
    const float* b11 = (const float*)d_in[3];
    const float* W12 = (const float*)d_in[4];
    const float* b12 = (const float*)d_in[5];
    const float* W13 = (const float*)d_in[6];
    const float* b13 = (const float*)d_in[7];
    const float* fcw = (const float*)d_in[8];
    const float* fcb = (const float*)d_in[9];
    float* out = (float*)d_out;

    const int N = in_sizes[0] / 3;
    const int E = in_sizes[1] / 2;
    const int* src = ei;
    const int* dst = ei + E;

    const int B = (N + RNODES - 1) / RNODES;      // 782 buckets
    const int S = (N + SNODES - 1) / SNODES;      // 25 supers
    const int capS = E / S + E / S / 16 + 1024;   // ~7% + 1K slack
    const int capB = E / B + E / B / 4 + 256;     // ~31% slack
    const size_t NC = (size_t)N * 32;

    // workspace layout (4-byte words); keep 8B alignment for row2/p4.
    float4*   p4      = (float4*)d_ws;                       // 4N words
    __half*   g       = (__half*)(p4 + N);                   // NC halfs = NC/2 words
    int2*     row2    = (int2*)(g + NC);                     // 2N words
    float*    dinv    = (float*)(row2 + N);                  // N
    int*      gcur1   = (int*)(dinv + N);                    // 32 (padded)
    int*      gcur2   = gcur1 + 32;                          // 800 (padded)
    unsigned* binned1 = (unsigned*)(gcur2 + 800);            // S*capS
    unsigned* binned2 = binned1 + (size_t)S * capS;          // B*capB
    int*      ssort   = (int*)(binned2 + (size_t)B * capB);  // B*capB
    __half*   gout    = (__half*)binned1;                    // NC halfs (binned1 dead)

    dim3 blk(256);
    dim3 grid_nc(((int)NC + 255) / 256);
    dim3 grid_n8(((N * 8) + 255) / 256);
    dim3 grid_e((E + CE - 1) / CE);
    dim3 grid_sc((S * capS + CE - 1) / CE);
    dim3 grid_b(B);

    // ---- preprocessing (no memsets, no prescan) ----
    k_init<<<dim3((B + 255) / 256), blk, 0, stream>>>(S, B, capS, capB, gcur1, gcur2);
    k_bin1<<<grid_e, blk, 0, stream>>>(src, dst, E, S, gcur1, binned1);
    k_bin2<<<grid_sc, blk, 0, stream>>>(binned1, gcur1, S, capS, gcur2, binned2);
    k_sortb2<<<grid_b, blk, 0, stream>>>(binned2, gcur2, capB, N, ssort, row2, dinv, x1, p4);

    // ---- layer 1 (+ W12 fused) ----
    k_l1g<<<grid_nc, blk, 0, stream>>>(row2, ssort, p4, dinv, W11, b11, W12, g, N);

    // ---- layer 2 aggregate + W13 gemv fused ----
    k_agg8g<<<grid_n8, blk, 0, stream>>>(row2, ssort, (const uint2*)g, dinv, b12, W13, (uint2*)gout, N);

    // ---- layer 3 + FC head ----
    k_agg8_fc<<<grid_n8, blk, 0, stream>>>(row2, ssort, (const uint2*)gout, dinv, b13, fcw, fcb, out, N);
}

// Round 5
// 202.359 us; speedup vs baseline: 1.1588x; 1.1588x over previous
//
#include <hip/hip_runtime.h>
#include <hip/hip_bf16.h>
#include <hip/hip_fp16.h>

// 3-layer GCN + FC head. No-prescan padded two-pass radix preprocessing:
//   k_init  : cursors = fixed region starts (super s: s*capS; bucket b: b*capB)
//   k_bin1  : bin edges by dst-super (25 regions), LDS rank, clustered writes
//   k_bin2  : bin by dst-bucket within super (782 padded regions; no div)
//   k_sortb2: LDS-staged single-read counting sort -> padded ssort +
//             row2[n]={beg,end} + dinv + fused p4 = dinv*x
// Layers:
//   k_l1g   : agg3 -> relu(.@W11+b11) -> @W12*dinv -> g (fp16)  [32 lanes/node]
//   k_agg16g: gather g (16 lanes/node, 8-deep) -> h=relu(dinv*acc+b12)
//             -> (h@W13)*dinv -> gout (fp16)  [LDS gemv fusion]
//   k_agg16_fc: gather gout -> relu(dinv*acc+b13).fcw + fcb -> out

#define RBITS  7
#define RNODES 128
#define SBITS  12
#define SNODES 4096
#define BPS    32
#define SMAX   32
#define CE     4096
#define EPT    16
#define LDSCAP 5632   // staged entries per bucket in k_sortb2 (22 KB)

// ---------- preprocessing ----------
__global__ void k_init(int S, int B, int capS, int capB,
                       int* __restrict__ gcur1, int* __restrict__ gcur2) {
    int t = blockIdx.x * blockDim.x + threadIdx.x;
    if (t < S) gcur1[t] = t * capS;
    if (t < B) gcur2[t] = t * capB;
}

__global__ void k_bin1(const int* __restrict__ src, const int* __restrict__ dst, int E, int S,
                       int* __restrict__ gcur1, unsigned* __restrict__ binned1) {
    __shared__ int cnt[SMAX * 8];
    __shared__ int repOff[SMAX * 8];
    __shared__ int runS[SMAX];
    int tid = threadIdx.x, rep = tid & 7;
    for (int i = tid; i < SMAX * 8; i += 256) cnt[i] = 0;
    __syncthreads();
    int e0 = blockIdx.x * CE;
    int pk[EPT], rnk[EPT], sup[EPT];
#pragma unroll
    for (int j = 0; j < EPT; j++) {
        int e = e0 + j * 256 + tid;
        if (e < E) {
            int d = __builtin_nontemporal_load(dst + e);
            sup[j] = d >> SBITS;
            pk[j]  = (__builtin_nontemporal_load(src + e) << SBITS) | (d & (SNODES - 1));
            rnk[j] = atomicAdd(&cnt[sup[j] * 8 + rep], 1);
        } else sup[j] = -1;
    }
    __syncthreads();
    if (tid < S) {
        int tot = 0;
#pragma unroll
        for (int r = 0; r < 8; r++) { repOff[tid * 8 + r] = tot; tot += cnt[tid * 8 + r]; }
        runS[tid] = tot ? atomicAdd(&gcur1[tid], tot) : 0;
    }
    __syncthreads();
#pragma unroll
    for (int j = 0; j < EPT; j++)
        if (sup[j] >= 0)
            binned1[runS[sup[j]] + repOff[sup[j] * 8 + rep] + rnk[j]] = (unsigned)pk[j];
}

__global__ void k_bin2(const unsigned* __restrict__ binned1, const int* __restrict__ fillEnd,
                       int S, int capS, int* __restrict__ gcur2, unsigned* __restrict__ binned2) {
    __shared__ int send[SMAX];
    __shared__ int cnt[64 * 4];
    __shared__ int repOff[64 * 4];
    __shared__ int runS[64];
    int tid = threadIdx.x, rep = tid & 3;
    if (tid < S) send[tid] = fillEnd[tid];
    for (int i = tid; i < 64 * 4; i += 256) cnt[i] = 0;
    __syncthreads();
    int i0 = blockIdx.x * CE;
    int s0 = i0 / capS;
    int bnd = (s0 + 1) * capS;      // a block spans at most 2 super-regions
    int Sc = S * capS;
    unsigned pk[EPT];
    int rnk[EPT], rb[EPT];
#pragma unroll
    for (int j = 0; j < EPT; j++) {
        int idx = i0 + j * 256 + tid;
        rb[j] = -1;
        if (idx < Sc) {
            int sp = s0 + (idx >= bnd ? 1 : 0);
            if (idx < send[sp]) {
                unsigned p = __builtin_nontemporal_load(binned1 + idx);
                int relB = ((sp - s0) << 5) | ((p >> RBITS) & (BPS - 1));
                pk[j] = p; rb[j] = relB;
                rnk[j] = atomicAdd(&cnt[relB * 4 + rep], 1);
            }
        }
    }
    __syncthreads();
    if (tid < 64) {
        int tot = 0;
#pragma unroll
        for (int r = 0; r < 4; r++) { repOff[tid * 4 + r] = tot; tot += cnt[tid * 4 + r]; }
        int sp = s0 + (tid >> 5);
        if (tot && sp < S) {
            int gb = sp * BPS + (tid & (BPS - 1));
            runS[tid] = atomicAdd(&gcur2[gb], tot);
        }
    }
    __syncthreads();
#pragma unroll
    for (int j = 0; j < EPT; j++)
        if (rb[j] >= 0) {
            unsigned p = pk[j];
            binned2[runS[rb[j]] + repOff[rb[j] * 4 + rep] + rnk[j]] =
                ((p >> SBITS) << RBITS) | (p & (RNODES - 1));
        }
}

// per-bucket counting sort, single global read via LDS staging ->
// padded ssort, row2[n]={beg,end}, dinv, p4=dinv*x
__global__ void k_sortb2(const unsigned* __restrict__ binned2, const int* __restrict__ gcur2,
                         int capB, int N, int* __restrict__ ssort,
                         int2* __restrict__ row2, float* __restrict__ dinv,
                         const float* __restrict__ x, float4* __restrict__ p4) {
    __shared__ int cnt[RNODES];
    __shared__ int loc[RNODES];
    __shared__ unsigned sbuf[LDSCAP];
    int b = blockIdx.x, tid = threadIdx.x;
    int beg = b * capB, end = gcur2[b];
    int tot = end - beg;
    int stg = tot < LDSCAP ? tot : LDSCAP;
    if (tid < RNODES) cnt[tid] = 0;
    __syncthreads();
    // single read: stage in LDS + count
    for (int i = tid; i < stg; i += 256) {
        unsigned p = __builtin_nontemporal_load(binned2 + beg + i);
        sbuf[i] = p;
        atomicAdd(&cnt[p & (RNODES - 1)], 1);
    }
    for (int i = LDSCAP + tid; i < tot; i += 256)   // overflow (normally empty)
        atomicAdd(&cnt[__builtin_nontemporal_load(binned2 + beg + i) & (RNODES - 1)], 1);
    __syncthreads();
    if (tid < RNODES) loc[tid] = cnt[tid];
    __syncthreads();
    for (int off = 1; off < RNODES; off <<= 1) {
        int v = 0;
        if (tid < RNODES && tid >= off) v = loc[tid - off];
        __syncthreads();
        if (tid < RNODES) loc[tid] += v;
        __syncthreads();
    }
    int n0 = b << RBITS;
    if (tid < RNODES) {
        int excl = loc[tid] - cnt[tid];
        loc[tid] = beg + excl;
        int n = n0 + tid;
        if (n < N) {
            row2[n] = make_int2(beg + excl, beg + excl + cnt[tid]);
            float dv = rsqrtf((float)cnt[tid] + 1.0f);   // +1 self loop
            dinv[n] = dv;
            p4[n] = make_float4(x[n * 3] * dv, x[n * 3 + 1] * dv,
                                x[n * 3 + 2] * dv, 0.f);
        }
    }
    if (tid < RNODES) cnt[tid] = 0;               // reuse as cursor
    __syncthreads();
    // scatter from LDS (no global re-read)
    for (int i = tid; i < stg; i += 256) {
        unsigned p = sbuf[i];
        int dl = (int)(p & (RNODES - 1));
        int r  = atomicAdd(&cnt[dl], 1);
        ssort[loc[dl] + r] = (int)(p >> RBITS);
    }
    for (int i = LDSCAP + tid; i < tot; i += 256) { // overflow (normally empty)
        unsigned p = __builtin_nontemporal_load(binned2 + beg + i);
        int dl = (int)(p & (RNODES - 1));
        int r  = atomicAdd(&cnt[dl], 1);
        ssort[loc[dl] + r] = (int)(p >> RBITS);
    }
}

// ---------- layer 1 (+W12 fused) ----------
__global__ void k_l1g(const int2* __restrict__ row2, const int* __restrict__ ssort,
                      const float4* __restrict__ p4, const float* __restrict__ dinv,
                      const float* __restrict__ W1, const float* __restrict__ b1,
                      const float* __restrict__ W2, __half* __restrict__ g2, int N) {
    __shared__ float sW1[96];
    __shared__ float sb1[32];
    __shared__ float sW2[1024];
    __shared__ float sh1[256];
    int tid = threadIdx.x;
    for (int i = tid; i < 1024; i += 256) sW2[i] = W2[i];
    if (tid < 96) sW1[tid] = W1[tid];
    if (tid < 32) sb1[tid] = b1[tid];
    __syncthreads();
    int t = blockIdx.x * 256 + tid;
    int n = t >> 5, c = t & 31;
    bool active = (n < N);
    float ax = 0.f, ay = 0.f, az = 0.f;
    float di = 0.f;
    float4 me = make_float4(0.f, 0.f, 0.f, 0.f);
    if (active) {
        me = p4[n];                 // independent loads hoisted above the gather
        di = dinv[n];
        int2 r = row2[n];
        for (int idx = r.x + c; idx < r.y; idx += 32) {
            float4 q = p4[__builtin_nontemporal_load(ssort + idx)];
            ax += q.x; ay += q.y; az += q.z;
        }
    }
#pragma unroll
    for (int off = 16; off; off >>= 1) {
        ax += __shfl_xor(ax, off, 32);
        ay += __shfl_xor(ay, off, 32);
        az += __shfl_xor(az, off, 32);
    }
    float h1 = 0.f;
    if (active) {
        ax = di * (ax + me.x); ay = di * (ay + me.y); az = di * (az + me.z);
        h1 = fmaxf(ax * sW1[c] + ay * sW1[32 + c] + az * sW1[64 + c] + sb1[c], 0.f);
    }
    sh1[tid] = h1;
    __syncthreads();
    if (!active) return;
    const float* hr = sh1 + (tid >> 5) * 32;
    float acc = 0.f;
#pragma unroll
    for (int k = 0; k < 32; k++) acc += hr[k] * sW2[k * 32 + c];
    g2[(size_t)n * 32 + c] = __float2half_rn(acc * di);
}

// ---------- layer 2 aggregate + W13 gemv fused ----------
// 16 lanes/node, lane = 2 channels, 8-deep MLP gather, ssort prefetch;
// h staged in LDS (pad 33), gemv (h@W13)*dinv -> gout fp16.
__global__ void k_agg16g(const int2* __restrict__ row2, const int* __restrict__ ssort,
                         const __half2* __restrict__ g2, const float* __restrict__ dinv,
                         const float* __restrict__ bias, const float* __restrict__ W3,
                         __half* __restrict__ gout, int N) {
    __shared__ float sW[1024];
    __shared__ float sh[16 * 33];
    int tid = threadIdx.x;
    for (int i = tid; i < 1024; i += 256) sW[i] = W3[i];
    int t = blockIdx.x * 256 + tid;
    int n = t >> 4, l = t & 15;
    int c0 = l * 2;
    bool act = (n < N);
    float di = 0.f;
    if (act) {
        float2 self = __half22float2(g2[(size_t)n * 16 + l]);  // hoisted
        di = dinv[n];                                           // hoisted
        int2 r = row2[n];
        int beg = r.x, end = r.y;
        float ax = 0.f, ay = 0.f, bx = 0.f, by = 0.f;
        float cx = 0.f, cy = 0.f, dx = 0.f, dy = 0.f;
        float ex = 0.f, ey = 0.f, fx = 0.f, fy = 0.f;
        float gx = 0.f, gy = 0.f, hx = 0.f, hy = 0.f;
        int base = beg;
        int m = end - base; if (m > 16) m = 16;
        int myS = (m > 0 && l < m) ? __builtin_nontemporal_load(ssort + base + l) : 0;
        while (base < end) {
            int nbase = base + 16;
            int nm = end - nbase; if (nm > 16) nm = 16;
            int nS = (nm > 0 && l < nm) ? __builtin_nontemporal_load(ssort + nbase + l) : 0;
            int i = 0;
            for (; i + 8 <= m; i += 8) {
                int s0 = __shfl(myS, i,     16);
                int s1 = __shfl(myS, i + 1, 16);
                int s2 = __shfl(myS, i + 2, 16);
                int s3 = __shfl(myS, i + 3, 16);
                int s4 = __shfl(myS, i + 4, 16);
                int s5 = __shfl(myS, i + 5, 16);
                int s6 = __shfl(myS, i + 6, 16);
                int s7 = __shfl(myS, i + 7, 16);
                float2 q0 = __half22float2(g2[(size_t)s0 * 16 + l]);
                float2 q1 = __half22float2(g2[(size_t)s1 * 16 + l]);
                float2 q2 = __half22float2(g2[(size_t)s2 * 16 + l]);
                float2 q3 = __half22float2(g2[(size_t)s3 * 16 + l]);
                float2 q4 = __half22float2(g2[(size_t)s4 * 16 + l]);
                float2 q5 = __half22float2(g2[(size_t)s5 * 16 + l]);
                float2 q6 = __half22float2(g2[(size_t)s6 * 16 + l]);
                float2 q7 = __half22float2(g2[(size_t)s7 * 16 + l]);
                ax += q0.x; ay += q0.y;
                bx += q1.x; by += q1.y;
                cx += q2.x; cy += q2.y;
                dx += q3.x; dy += q3.y;
                ex += q4.x; ey += q4.y;
                fx += q5.x; fy += q5.y;
                gx += q6.x; gy += q6.y;
                hx += q7.x; hy += q7.y;
            }
            for (; i + 4 <= m; i += 4) {
                int s0 = __shfl(myS, i,     16);
                int s1 = __shfl(myS, i + 1, 16);
                int s2 = __shfl(myS, i + 2, 16);
                int s3 = __shfl(myS, i + 3, 16);
                float2 q0 = __half22float2(g2[(size_t)s0 * 16 + l]);
                float2 q1 = __half22float2(g2[(size_t)s1 * 16 + l]);
                float2 q2 = __half22float2(g2[(size_t)s2 * 16 + l]);
                float2 q3 = __half22float2(g2[(size_t)s3 * 16 + l]);
                ax += q0.x; ay += q0.y;
                bx += q1.x; by += q1.y;
                cx += q2.x; cy += q2.y;
                dx += q3.x; dy += q3.y;
            }
            for (; i < m; i++) {
                int s = __shfl(myS, i, 16);
                float2 q = __half22float2(g2[(size_t)s * 16 + l]);
                ax += q.x; ay += q.y;
            }
            base = nbase; m = nm; myS = nS;
        }
        float sx = (((ax + bx) + (cx + dx)) + ((ex + fx) + (gx + hx))) + self.x;
        float sy = (((ay + by) + (cy + dy)) + ((ey + fy) + (gy + hy))) + self.y;
        int nn = tid >> 4;
        sh[nn * 33 + c0]     = fmaxf(di * sx + bias[c0], 0.f);
        sh[nn * 33 + c0 + 1] = fmaxf(di * sy + bias[c0 + 1], 0.f);
    }
    __syncthreads();
    if (!act) return;
    const float* hr = sh + (tid >> 4) * 33;
    float a0 = 0.f, a1 = 0.f;
#pragma unroll
    for (int k = 0; k < 32; k++) {
        float hv = hr[k];
        float2 w = *(const float2*)(sW + k * 32 + c0);
        a0 += hv * w.x; a1 += hv * w.y;
    }
    __half2 o = __floats2half2_rn(a0 * di, a1 * di);
    *(__half2*)(gout + (size_t)n * 32 + c0) = o;
}

// ---------- layer 3 aggregate + FC head: 8-deep MLP structure ----------
__global__ void k_agg16_fc(const int2* __restrict__ row2, const int* __restrict__ ssort,
                           const __half2* __restrict__ g2, const float* __restrict__ dinv,
                           const float* __restrict__ bias, const float* __restrict__ fcw,
                           const float* __restrict__ fcb, float* __restrict__ out, int N) {
    int t = blockIdx.x * blockDim.x + threadIdx.x;
    int n = t >> 4, l = t & 15;
    if (n >= N) return;
    float2 self = __half22float2(g2[(size_t)n * 16 + l]);   // hoisted
    float di = dinv[n];                                      // hoisted
    int2 r = row2[n];
    int beg = r.x, end = r.y;
    float ax = 0.f, ay = 0.f, bx = 0.f, by = 0.f;
    float cx = 0.f, cy = 0.f, dx = 0.f, dy = 0.f;
    float ex = 0.f, ey = 0.f, fx = 0.f, fy = 0.f;
    float gx = 0.f, gy = 0.f, hx = 0.f, hy = 0.f;
    int base = beg;
    int m = end - base; if (m > 16) m = 16;
    int myS = (m > 0 && l < m) ? __builtin_nontemporal_load(ssort + base + l) : 0;
    while (base < end) {
        int nbase = base + 16;
        int nm = end - nbase; if (nm > 16) nm = 16;
        int nS = (nm > 0 && l < nm) ? __builtin_nontemporal_load(ssort + nbase + l) : 0;
        int i = 0;
        for (; i + 8 <= m; i += 8) {
            int s0 = __shfl(myS, i,     16);
            int s1 = __shfl(myS, i + 1, 16);
            int s2 = __shfl(myS, i + 2, 16);
            int s3 = __shfl(myS, i + 3, 16);
            int s4 = __shfl(myS, i + 4, 16);
            int s5 = __shfl(myS, i + 5, 16);
            int s6 = __shfl(myS, i + 6, 16);
            int s7 = __shfl(myS, i + 7, 16);
            float2 q0 = __half22float2(g2[(size_t)s0 * 16 + l]);
            float2 q1 = __half22float2(g2[(size_t)s1 * 16 + l]);
            float2 q2 = __half22float2(g2[(size_t)s2 * 16 + l]);
            float2 q3 = __half22float2(g2[(size_t)s3 * 16 + l]);
            float2 q4 = __half22float2(g2[(size_t)s4 * 16 + l]);
            float2 q5 = __half22float2(g2[(size_t)s5 * 16 + l]);
            float2 q6 = __half22float2(g2[(size_t)s6 * 16 + l]);
            float2 q7 = __half22float2(g2[(size_t)s7 * 16 + l]);
            ax += q0.x; ay += q0.y;
            bx += q1.x; by += q1.y;
            cx += q2.x; cy += q2.y;
            dx += q3.x; dy += q3.y;
            ex += q4.x; ey += q4.y;
            fx += q5.x; fy += q5.y;
            gx += q6.x; gy += q6.y;
            hx += q7.x; hy += q7.y;
        }
        for (; i + 4 <= m; i += 4) {
            int s0 = __shfl(myS, i,     16);
            int s1 = __shfl(myS, i + 1, 16);
            int s2 = __shfl(myS, i + 2, 16);
            int s3 = __shfl(myS, i + 3, 16);
            float2 q0 = __half22float2(g2[(size_t)s0 * 16 + l]);
            float2 q1 = __half22float2(g2[(size_t)s1 * 16 + l]);
            float2 q2 = __half22float2(g2[(size_t)s2 * 16 + l]);
            float2 q3 = __half22float2(g2[(size_t)s3 * 16 + l]);
            ax += q0.x; ay += q0.y;
            bx += q1.x; by += q1.y;
            cx += q2.x; cy += q2.y;
            dx += q3.x; dy += q3.y;
        }
        for (; i < m; i++) {
            int s = __shfl(myS, i, 16);
            float2 q = __half22float2(g2[(size_t)s * 16 + l]);
            ax += q.x; ay += q.y;
        }
        base = nbase; m = nm; myS = nS;
    }
    float sx = (((ax + bx) + (cx + dx)) + ((ex + fx) + (gx + hx))) + self.x;
    float sy = (((ay + by) + (cy + dy)) + ((ey + fy) + (gy + hy))) + self.y;
    int c0 = l * 2;
    float v = fmaxf(di * sx + bias[c0], 0.f) * fcw[c0]
            + fmaxf(di * sy + bias[c0 + 1], 0.f) * fcw[c0 + 1];
    v += __shfl_down(v, 8, 16);
    v += __shfl_down(v, 4, 16);
    v += __shfl_down(v, 2, 16);
    v += __shfl_down(v, 1, 16);
    if (l == 0) out[n] = v + fcb[0];
}

extern "C" void kernel_launch(void* const* d_in, const int* in_sizes, int n_in,
                              void* d_out, int out_size, void* d_ws, size_t ws_size,
                              hipStream_t stream) {
    const float* x1  = (const float*)d_in[0];
    const int*   ei  = (const int*)d_in[1];
    const float* W11 = (const float*)d_in[2];
    const float* b11 = (const float*)d_in[3];
    const float* W12 = (const float*)d_in[4];
    const float* b12 = (const float*)d_in[5];
    const float* W13 = (const float*)d_in[6];
    const float* b13 = (const float*)d_in[7];
    const float* fcw = (const float*)d_in[8];
    const float* fcb = (const float*)d_in[9];
    float* out = (float*)d_out;

    const int N = in_sizes[0] / 3;
    const int E = in_sizes[1] / 2;
    const int* src = ei;
    const int* dst = ei + E;

    const int B = (N + RNODES - 1) / RNODES;      // 782 buckets
    const int S = (N + SNODES - 1) / SNODES;      // 25 supers
    const int capS = E / S + E / S / 16 + 1024;   // ~7% + 1K slack
    const int capB = E / B + E / B / 4 + 256;     // ~31% slack
    const size_t NC = (size_t)N * 32;

    // workspace layout (4-byte words); keep 8B alignment for row2/p4.
    float4*   p4      = (float4*)d_ws;                       // 4N words
    __half*   g       = (__half*)(p4 + N);                   // NC halfs = NC/2 words
    int2*     row2    = (int2*)(g + NC);                     // 2N words
    float*    dinv    = (float*)(row2 + N);                  // N
    int*      gcur1   = (int*)(dinv + N);                    // 32 (padded)
    int*      gcur2   = gcur1 + 32;                          // 800 (padded)
    unsigned* binned1 = (unsigned*)(gcur2 + 800);            // S*capS
    unsigned* binned2 = binned1 + (size_t)S * capS;          // B*capB
    int*      ssort   = (int*)(binned2 + (size_t)B * capB);  // B*capB
    __half*   gout    = (__half*)binned1;                    // NC halfs (binned1 dead)

    dim3 blk(256);
    dim3 grid_nc(((int)NC + 255) / 256);
    dim3 grid_n16(((N * 16) + 255) / 256);
    dim3 grid_e((E + CE - 1) / CE);
    dim3 grid_sc((S * capS + CE - 1) / CE);
    dim3 grid_b(B);

    // ---- preprocessing (no memsets, no prescan) ----
    k_init<<<dim3((B + 255) / 256), blk, 0, stream>>>(S, B, capS, capB, gcur1, gcur2);
    k_bin1<<<grid_e, blk, 0, stream>>>(src, dst, E, S, gcur1, binned1);
    k_bin2<<<grid_sc, blk, 0, stream>>>(binned1, gcur1, S, capS, gcur2, binned2);
    k_sortb2<<<grid_b, blk, 0, stream>>>(binned2, gcur2, capB, N, ssort, row2, dinv, x1, p4);

    // ---- layer 1 (+ W12 fused) ----
    k_l1g<<<grid_nc, blk, 0, stream>>>(row2, ssort, p4, dinv, W11, b11, W12, g, N);

    // ---- layer 2 aggregate + W13 gemv fused ----
    k_agg16g<<<grid_n16, blk, 0, stream>>>(row2, ssort, (const __half2*)g, dinv, b12, W13, gout, N);

    // ---- layer 3 + FC head ----
    k_agg16_fc<<<grid_n16, blk, 0, stream>>>(row2, ssort, (const __half2*)gout, dinv, b13, fcw, fcb, out, N);
}